// Round 1
// baseline (892.828 us; speedup 1.0000x reference)
//
#include <hip/hip_runtime.h>
#include <math.h>

#define LOG2E 1.4426950408889634f

constexpr int B_ = 4, N_ = 2048, H_ = 4, D_ = 32, HD_ = 128;

// x[BN,K] @ Wl/Wr[K,128] + bl/br -> xl,xr stored as [B,H,N,D]
__global__ __launch_bounds__(256) void k_linear(
    const float* __restrict__ x,
    const float* __restrict__ Wl, const float* __restrict__ bl,
    const float* __restrict__ Wr, const float* __restrict__ br,
    float* __restrict__ xl, float* __restrict__ xr, int K)
{
    __shared__ __align__(16) float xs[32 * 128];
    const int tid = threadIdx.x;
    const int r0 = blockIdx.x * 32;                 // 32 rows (= b*N+n) per block
    const float4* src = (const float4*)(x + (size_t)r0 * K);
    float4* dst = (float4*)xs;
    for (int idx = tid; idx < 8 * K; idx += 256) dst[idx] = src[idx];
    __syncthreads();

    const int c  = tid & 127;                       // output col 0..127
    const int rg = tid >> 7;                        // row group 0..1 (16 rows each)
    float accl[16], accr[16];
    const float blv = bl[c], brv = br[c];
    #pragma unroll
    for (int r = 0; r < 16; r++) { accl[r] = blv; accr[r] = brv; }
    #pragma unroll 8
    for (int k = 0; k < K; k++) {
        const float wl = Wl[k * HD_ + c];
        const float wr = Wr[k * HD_ + c];
        #pragma unroll
        for (int r = 0; r < 16; r++) {
            const float xv = xs[(rg * 16 + r) * K + k];
            accl[r] = fmaf(xv, wl, accl[r]);
            accr[r] = fmaf(xv, wr, accr[r]);
        }
    }
    const int h = c >> 5, d = c & 31;
    #pragma unroll
    for (int r = 0; r < 16; r++) {
        const int row = r0 + rg * 16 + r;           // = b*N + n
        const int b = row >> 11, n = row & (N_ - 1);
        const size_t o = (((size_t)(b * H_ + h)) * N_ + n) * D_ + d;
        xl[o] = accl[r];
        xr[o] = accr[r];
    }
}

// u = 0.6*log2e * att_h . xl_row ; v = same for xr   (rank-1 part of the score)
__global__ __launch_bounds__(256) void k_uv(
    const float* __restrict__ xl, const float* __restrict__ xr,
    const float* __restrict__ att,
    float* __restrict__ u, float* __restrict__ v)
{
    const int idx = blockIdx.x * 256 + threadIdx.x; // [0, B*H*N)
    const int h = (idx / N_) & (H_ - 1);
    const float4* a4 = (const float4*)(att + h * D_);
    const float4* l4 = (const float4*)(xl + (size_t)idx * D_);
    const float4* r4 = (const float4*)(xr + (size_t)idx * D_);
    float su = 0.f, sv = 0.f;
    #pragma unroll
    for (int q = 0; q < 8; q++) {
        const float4 a = a4[q], lv = l4[q], rv = r4[q];
        su += a.x * lv.x + a.y * lv.y + a.z * lv.z + a.w * lv.w;
        sv += a.x * rv.x + a.y * rv.y + a.z * rv.z + a.w * rv.w;
    }
    u[idx] = 0.6f * LOG2E * su;
    v[idx] = 0.6f * LOG2E * sv;
}

// Flash-style GATv2 attention. Lane pair shares one target row i (d split 16+16).
// e_ij(scaled by log2e) = u_j + v_i + sum_d tc_d * |xl_jd + xr_id|
__global__ __launch_bounds__(128) void k_attn(
    const float* __restrict__ xl, const float* __restrict__ xr,
    const float* __restrict__ u, const float* __restrict__ v,
    const float* __restrict__ att, float* __restrict__ out)
{
    __shared__ __align__(16) float xs[64 * D_];
    __shared__ float us[64];
    const int tid = threadIdx.x;
    const int r = tid >> 1, dh = tid & 1;
    const int bh = blockIdx.x >> 5;                 // 32 tiles per (b,h)
    const int i  = (blockIdx.x & 31) * 64 + r;
    const int h  = bh & (H_ - 1);
    const size_t rowbase = ((size_t)bh * N_ + i) * D_ + dh * 16;

    float xrg[16], tc[16];
    #pragma unroll
    for (int q4 = 0; q4 < 4; q4++) {
        const float4 xv = *(const float4*)(xr + rowbase + q4 * 4);
        const float4 av = *(const float4*)(att + (size_t)h * D_ + dh * 16 + q4 * 4);
        xrg[4*q4+0] = xv.x; xrg[4*q4+1] = xv.y; xrg[4*q4+2] = xv.z; xrg[4*q4+3] = xv.w;
        const float C = 0.4f * LOG2E;
        tc[4*q4+0] = C * av.x; tc[4*q4+1] = C * av.y; tc[4*q4+2] = C * av.z; tc[4*q4+3] = C * av.w;
    }
    const float vi = v[(size_t)bh * N_ + i];

    float m = -INFINITY, l = 0.f;
    float o[16];
    #pragma unroll
    for (int k = 0; k < 16; k++) o[k] = 0.f;

    for (int j0 = 0; j0 < N_; j0 += 64) {
        const float4* src = (const float4*)(xl + ((size_t)bh * N_ + j0) * D_);
        #pragma unroll
        for (int it = 0; it < 4; it++)
            ((float4*)xs)[tid + 128 * it] = src[tid + 128 * it];
        if (tid < 64) us[tid] = u[(size_t)bh * N_ + j0 + tid];
        __syncthreads();

        #pragma unroll
        for (int jj = 0; jj < 64; jj += 16) {
            float e16[16];
            #pragma unroll
            for (int q = 0; q < 16; q++) {
                const float4* row4 = (const float4*)(xs + (jj + q) * D_ + dh * 16);
                float rv[16];
                #pragma unroll
                for (int q4 = 0; q4 < 4; q4++) {
                    const float4 t4 = row4[q4];
                    rv[4*q4+0] = t4.x; rv[4*q4+1] = t4.y; rv[4*q4+2] = t4.z; rv[4*q4+3] = t4.w;
                }
                float p0 = 0.f, p1 = 0.f, p2 = 0.f, p3 = 0.f;
                #pragma unroll
                for (int k = 0; k < 4; k++) {
                    const float z0 = rv[k]      + xrg[k];
                    const float z1 = rv[k + 4]  + xrg[k + 4];
                    const float z2 = rv[k + 8]  + xrg[k + 8];
                    const float z3 = rv[k + 12] + xrg[k + 12];
                    p0 = fmaf(tc[k],      fabsf(z0), p0);
                    p1 = fmaf(tc[k + 4],  fabsf(z1), p1);
                    p2 = fmaf(tc[k + 8],  fabsf(z2), p2);
                    p3 = fmaf(tc[k + 12], fabsf(z3), p3);
                }
                float part = (p0 + p1) + (p2 + p3);
                part += __shfl_xor(part, 1);
                e16[q] = part + us[jj + q] + vi;
            }
            // tile max
            float t0 = fmaxf(fmaxf(fmaxf(e16[0], e16[1]), fmaxf(e16[2], e16[3])),
                             fmaxf(fmaxf(e16[4], e16[5]), fmaxf(e16[6], e16[7])));
            float t1 = fmaxf(fmaxf(fmaxf(e16[8], e16[9]), fmaxf(e16[10], e16[11])),
                             fmaxf(fmaxf(e16[12], e16[13]), fmaxf(e16[14], e16[15])));
            const float mn = fmaxf(m, fmaxf(t0, t1));
            const float al = exp2f(m - mn);
            m = mn;
            l *= al;
            #pragma unroll
            for (int k = 0; k < 16; k++) o[k] *= al;
            #pragma unroll
            for (int q = 0; q < 16; q++) {
                const float p = exp2f(e16[q] - m);
                l += p;
                const float4* row4 = (const float4*)(xs + (jj + q) * D_ + dh * 16);
                #pragma unroll
                for (int q4 = 0; q4 < 4; q4++) {
                    const float4 t4 = row4[q4];
                    o[4*q4+0] = fmaf(p, t4.x, o[4*q4+0]);
                    o[4*q4+1] = fmaf(p, t4.y, o[4*q4+1]);
                    o[4*q4+2] = fmaf(p, t4.z, o[4*q4+2]);
                    o[4*q4+3] = fmaf(p, t4.w, o[4*q4+3]);
                }
            }
        }
        __syncthreads();
    }

    const float inv = 1.f / l;
    #pragma unroll
    for (int q4 = 0; q4 < 4; q4++) {
        float4 w;
        w.x = o[4*q4+0] * inv; w.y = o[4*q4+1] * inv;
        w.z = o[4*q4+2] * inv; w.w = o[4*q4+3] * inv;
        *(float4*)(out + rowbase + q4 * 4) = w;
    }
}

// bias add + LayerNorm(128) (+optional ReLU); input [B,H,N,32] -> output [B,N,128]
__global__ __launch_bounds__(64) void k_ln(
    const float* __restrict__ ain, const float* __restrict__ bias,
    const float* __restrict__ g, const float* __restrict__ bta,
    float* __restrict__ outp, int do_relu)
{
    const int row = blockIdx.x;                     // b*N+n
    const int b = row >> 11, n = row & (N_ - 1);
    const int t = threadIdx.x;
    const int c0 = t, c1 = t + 64;
    const size_t i0 = (((size_t)(b * H_ + (c0 >> 5))) * N_ + n) * D_ + (c0 & 31);
    const size_t i1 = (((size_t)(b * H_ + (c1 >> 5))) * N_ + n) * D_ + (c1 & 31);
    const float x0 = ain[i0] + bias[c0];
    const float x1 = ain[i1] + bias[c1];
    float s = x0 + x1;
    #pragma unroll
    for (int w = 1; w < 64; w <<= 1) s += __shfl_xor(s, w);
    const float mu = s * (1.f / 128.f);
    const float d0 = x0 - mu, d1 = x1 - mu;
    float q = d0 * d0 + d1 * d1;
    #pragma unroll
    for (int w = 1; w < 64; w <<= 1) q += __shfl_xor(q, w);
    const float rstd = rsqrtf(q * (1.f / 128.f) + 1e-5f);
    float y0 = d0 * rstd * g[c0] + bta[c0];
    float y1 = d1 * rstd * g[c1] + bta[c1];
    if (do_relu) { y0 = fmaxf(y0, 0.f); y1 = fmaxf(y1, 0.f); }
    outp[(size_t)row * HD_ + c0] = y0;
    outp[(size_t)row * HD_ + c1] = y1;
}

extern "C" void kernel_launch(void* const* d_in, const int* in_sizes, int n_in,
                              void* d_out, int out_size, void* d_ws, size_t ws_size,
                              hipStream_t stream) {
    const float* x    = (const float*)d_in[0];
    // d_in[1] = embedding (unused: adjacency is dense and values discarded)
    const float* Wl1  = (const float*)d_in[2];
    const float* bl1  = (const float*)d_in[3];
    const float* Wr1  = (const float*)d_in[4];
    const float* br1  = (const float*)d_in[5];
    const float* att1 = (const float*)d_in[6];
    const float* bias1= (const float*)d_in[7];
    const float* ln1g = (const float*)d_in[8];
    const float* ln1b = (const float*)d_in[9];
    const float* Wl2  = (const float*)d_in[10];
    const float* bl2  = (const float*)d_in[11];
    const float* Wr2  = (const float*)d_in[12];
    const float* br2  = (const float*)d_in[13];
    const float* att2 = (const float*)d_in[14];
    const float* bias2= (const float*)d_in[15];
    const float* ln2g = (const float*)d_in[16];
    const float* ln2b = (const float*)d_in[17];

    float* ws = (float*)d_ws;
    const size_t M = (size_t)B_ * H_ * N_ * D_;     // 1,048,576
    float* xl = ws;
    float* xr = xl + M;
    float* u  = xr + M;
    float* v  = u + B_ * H_ * N_;
    float* ao = v + B_ * H_ * N_;
    float* h  = ao + M;
    float* outf = (float*)d_out;

    const int BN = B_ * N_;                          // 8192
    // ---- layer 1 ----
    k_linear<<<BN / 32, 256, 0, stream>>>(x, Wl1, bl1, Wr1, br1, xl, xr, 32);
    k_uv<<<(B_ * H_ * N_) / 256, 256, 0, stream>>>(xl, xr, att1, u, v);
    k_attn<<<(B_ * H_ * N_) / 64, 128, 0, stream>>>(xl, xr, u, v, att1, ao);
    k_ln<<<BN, 64, 0, stream>>>(ao, bias1, ln1g, ln1b, h, 1);
    // ---- layer 2 ----
    k_linear<<<BN / 32, 256, 0, stream>>>(h, Wl2, bl2, Wr2, br2, xl, xr, 128);
    k_uv<<<(B_ * H_ * N_) / 256, 256, 0, stream>>>(xl, xr, att2, u, v);
    k_attn<<<(B_ * H_ * N_) / 64, 128, 0, stream>>>(xl, xr, u, v, att2, ao);
    k_ln<<<BN, 64, 0, stream>>>(ao, bias2, ln2g, ln2b, outf, 0);
}